// Round 17
// baseline (152.342 us; speedup 1.0000x reference)
//
#include <hip/hip_runtime.h>
#include <hip/hip_fp16.h>
#include <math.h>

// Problem constants
#define NB 392      // n = b*oh*ow = 2*14*14
#define NI 288      // K*K*B = 9*32
#define NC 32       // C
#define NQ 16       // PSIZE
#define CQ 512      // NC*NQ
#define CH 544      // B*(PSIZE+1)
#define EPSV 1e-6f

// votes are fp8 e4m3 scaled by 32; routing descales algebraically.
#define VSCALE 32.0f
#define VINV (1.0f / 32.0f)

// out layout (floats)
#define OFF_AOUT 200704       // NB*CQ
#define OFF_CAT  213248       // OFF_AOUT + NB*NC

#define RT_THREADS 512
#define RT_WAVES 8

typedef _Float16 v4h __attribute__((ext_vector_type(4)));
typedef float v4f __attribute__((ext_vector_type(4)));
typedef float v2f __attribute__((ext_vector_type(2)));

// ---------------------------------------------------------------------------
// Gather from x via the unfold channel-major reinterpret.
__device__ __forceinline__ float gather_x(const float* __restrict__ x, int n, int j) {
    int c_idx = j / 9;
    int rem = j - c_idx * 9;
    int ki = rem / 3;
    int kj = rem - ki * 3;
    int b_ = n / 196;
    int rest = n - b_ * 196;
    int yy = rest / 14;
    int xx = rest - yy * 14;
    int iy = yy + ki - 1;
    int ix = xx + kj - 1;
    float v = 0.f;
    if ((unsigned)iy < 14u && (unsigned)ix < 14u)
        v = x[((b_ * 14 + iy) * 14 + ix) * CH + c_idx];
    return v;
}

// ---------------------------------------------------------------------------
// votes via swapped-operand mfma 16x16x16 f16, reading wts directly.
// (Unchanged from round 16 -- best measured votes structure.)
__global__ __launch_bounds__(256) void votes_k(const float* __restrict__ x,
                                               const float* __restrict__ wts,
                                               uchar* __restrict__ votes) {
    __shared__ uint tile[64 * 36];      // 9 KB, pitch 36 dwords (144 B)
    int mtt = blockIdx.x;         // 0..6
    int i = blockIdx.y;           // 0..287
    int t = threadIdx.x;
    int wv = t >> 6;
    int l = t & 63;
    int col = l & 15;
    int quad = l >> 4;

    int n_row = mtt * 64 + wv * 16 + col;
    v4h av = {};
    if (n_row < NB) {
        int jb = (i >> 5) * CH + (i & 31) * 16 + quad * 4;
#pragma unroll
        for (int kk = 0; kk < 4; ++kk)
            av[kk] = (_Float16)gather_x(x, n_row, jb + kk);
    }

    const float* wb = wts + (size_t)i * 8192 + quad * 64 + col;
    const uchar* tileb = (const uchar*)tile;

    for (int ch = 0; ch < 4; ++ch) {
#pragma unroll
        for (int c8 = 0; c8 < 8; ++c8) {
            int ct = ch * 8 + c8;
            const float* wp = wb + ct * 256;
            v4h bv;
            bv[0] = (_Float16)wp[0];
            bv[1] = (_Float16)wp[16];
            bv[2] = (_Float16)wp[32];
            bv[3] = (_Float16)wp[48];
            v4f acc = {0.f, 0.f, 0.f, 0.f};
            acc = __builtin_amdgcn_mfma_f32_16x16x16f16(bv, av, acc, 0, 0, 0);
            uint u = __builtin_amdgcn_cvt_pk_fp8_f32(acc[0] * VSCALE, acc[1] * VSCALE, 0, false);
            u = __builtin_amdgcn_cvt_pk_fp8_f32(acc[2] * VSCALE, acc[3] * VSCALE, u, true);
            tile[(wv * 16 + col) * 36 + c8 * 4 + quad] = u;
        }
        __syncthreads();
#pragma unroll
        for (int k = 0; k < 2; ++k) {
            int idx = k * 256 + t;
            int row = idx >> 3;
            int off = idx & 7;
            int n_out = mtt * 64 + row;
            if (n_out < NB) {
                uint4 d = *(const uint4*)&tileb[row * 144 + off * 16];
                *(uint4*)(votes + (((size_t)n_out * NI + i) << 9) + ch * 128 + off * 16) = d;
            }
        }
        __syncthreads();
    }
}

// ---------------------------------------------------------------------------
// LDS-RESIDENT routing: one n's votes (288x512 fp8 = 144 KB) fit in CDNA4's
// 160 KB LDS. Pass 0 streams votes from global ONCE (decode + iter-0
// accumulate + deposit raw fp8 rows into vlds); iters 1-2 replay from LDS.
// Eliminates 2 of 3 global vote sweeps. The 16 KB sred tree-reduce is
// replaced by LDS atomicAdd into a 2 KB sacc (fits the LDS budget; order
// nondeterminism ~1e-6, buried under fp8 quantization error).
// LDS total ~149.3 KB -> 1 block/CU, 8 waves.
__global__ __launch_bounds__(RT_THREADS) void routing_k(const uchar* __restrict__ votes,
                                                        const float* __restrict__ x,
                                                        float* __restrict__ out) {
    __shared__ uchar vlds[NI * 512];    // 147456 B: this n's votes, fp8
    __shared__ float afs[NI];
    __shared__ float sacc[CQ];          // 2 KB, [q*32+c], atomic-accumulated
    __shared__ float vj[CQ];            // [q*32+c]
    __shared__ float aout_s[NC];

    int n = blockIdx.x;
    int t = threadIdx.x;
    int wv = t >> 6;      // 0..7
    int l = t & 63;
    int c = l & 31;
    int g = l >> 5;

    if (t < NI) {
        int j = (t >> 5) * CH + 512 + (t & 31);
        float v = gather_x(x, n, j);
        float a = fminf(fmaxf(v, 1e-4f), 1.0f);
        afs[t] = a / (a + EPSV);
    }

    const uchar* vb = votes + (size_t)n * NI * 512;
    float vjr[16];    // cumulative vj, PRE-SCALED by 1/32
    float sreg[16];

#define VROW(S) (((const uint4*)(vb + ((size_t)(((((S) << 3) + wv) << 1) + g) << 9)))[c])

    for (int iter = 0; iter < 3; ++iter) {
        sacc[t] = 0.f;        // 512 threads == CQ; also makes afs visible
        __syncthreads();
#pragma unroll
        for (int q = 0; q < 16; ++q) sreg[q] = 0.f;

        if (iter == 0) {
            // stream global -> LDS deposit + iter-0 accumulate
            uint4 f0 = VROW(0), f1 = VROW(1), f2 = VROW(2), f3 = VROW(3);
#pragma clang loop unroll_count(2)
            for (int s = 0; s < 18; ++s) {
                int i = ((s << 3) + wv) * 2 + g;
                uint4 cur = f0;
                f0 = f1; f1 = f2; f2 = f3;
                if (s + 4 < 18) f3 = VROW(s + 4);
                *(uint4*)&vlds[i * 512 + c * 16] = cur;   // contiguous 512 B/half-wave
                float vt[16];
                {
                    v2f p;
                    p = __builtin_amdgcn_cvt_pk_f32_fp8(cur.x, false); vt[0] = p[0];  vt[1] = p[1];
                    p = __builtin_amdgcn_cvt_pk_f32_fp8(cur.x, true);  vt[2] = p[0];  vt[3] = p[1];
                    p = __builtin_amdgcn_cvt_pk_f32_fp8(cur.y, false); vt[4] = p[0];  vt[5] = p[1];
                    p = __builtin_amdgcn_cvt_pk_f32_fp8(cur.y, true);  vt[6] = p[0];  vt[7] = p[1];
                    p = __builtin_amdgcn_cvt_pk_f32_fp8(cur.z, false); vt[8] = p[0];  vt[9] = p[1];
                    p = __builtin_amdgcn_cvt_pk_f32_fp8(cur.z, true);  vt[10] = p[0]; vt[11] = p[1];
                    p = __builtin_amdgcn_cvt_pk_f32_fp8(cur.w, false); vt[12] = p[0]; vt[13] = p[1];
                    p = __builtin_amdgcn_cvt_pk_f32_fp8(cur.w, true);  vt[14] = p[0]; vt[15] = p[1];
                }
                float cij = afs[i] * (1.0f / 32.0f);
#pragma unroll
                for (int q = 0; q < 16; ++q) sreg[q] += cij * vt[q];
            }
        } else {
            // replay from LDS
#pragma clang loop unroll_count(2)
            for (int s = 0; s < 18; ++s) {
                int i = ((s << 3) + wv) * 2 + g;
                uint4 cur = *(const uint4*)&vlds[i * 512 + c * 16];
                float vt[16];
                {
                    v2f p;
                    p = __builtin_amdgcn_cvt_pk_f32_fp8(cur.x, false); vt[0] = p[0];  vt[1] = p[1];
                    p = __builtin_amdgcn_cvt_pk_f32_fp8(cur.x, true);  vt[2] = p[0];  vt[3] = p[1];
                    p = __builtin_amdgcn_cvt_pk_f32_fp8(cur.y, false); vt[4] = p[0];  vt[5] = p[1];
                    p = __builtin_amdgcn_cvt_pk_f32_fp8(cur.y, true);  vt[6] = p[0];  vt[7] = p[1];
                    p = __builtin_amdgcn_cvt_pk_f32_fp8(cur.z, false); vt[8] = p[0];  vt[9] = p[1];
                    p = __builtin_amdgcn_cvt_pk_f32_fp8(cur.z, true);  vt[10] = p[0]; vt[11] = p[1];
                    p = __builtin_amdgcn_cvt_pk_f32_fp8(cur.w, false); vt[12] = p[0]; vt[13] = p[1];
                    p = __builtin_amdgcn_cvt_pk_f32_fp8(cur.w, true);  vt[14] = p[0]; vt[15] = p[1];
                }
                float ah = 0.f;   // vt(raw) . vjr(pre-scaled) == true dot
#pragma unroll
                for (int q = 0; q < 16; ++q) ah += vt[q] * vjr[q];
                float e = __expf(ah);
                float ssum = e;
                ssum += __shfl_xor(ssum, 1);
                ssum += __shfl_xor(ssum, 2);
                ssum += __shfl_xor(ssum, 4);
                ssum += __shfl_xor(ssum, 8);
                ssum += __shfl_xor(ssum, 16);
                float cij = e * __builtin_amdgcn_rcpf(ssum) * afs[i];
#pragma unroll
                for (int q = 0; q < 16; ++q) sreg[q] += cij * vt[q];
            }
        }

        // fold g-halves, then atomic-accumulate into sacc (bank==c: clean)
#pragma unroll
        for (int q = 0; q < 16; ++q) sreg[q] += __shfl_xor(sreg[q], 32);
        if (g == 0) {
#pragma unroll
            for (int q = 0; q < 16; ++q) atomicAdd(&sacc[q * 32 + c], sreg[q]);
        }
        __syncthreads();

        // squash (threads 0..31, one c each; element (c,q) at sacc[q*32+c])
        if (t < NC) {
            float s2 = 0.f;
            float sv[16];
#pragma unroll
            for (int q = 0; q < 16; ++q) {
                float s = sacc[q * 32 + t] * VINV;   // descale x32 fp8 encoding
                sv[q] = s;
                s2 += s * s;
            }
            float f = (s2 / (1.f + s2)) / sqrtf(s2 + EPSV);
            float vn2 = 0.f;
#pragma unroll
            for (int q = 0; q < 16; ++q) {
                float v = f * sv[q];
                vj[q * 32 + t] = v;
                vn2 += v * v;
            }
            if (iter == 2) {
                float ao = sqrtf(vn2 + EPSV);
                ao = fminf(fmaxf(ao, 1e-4f), 1.f - 1e-4f);
                aout_s[t] = ao;
            }
        }
        __syncthreads();
        if (iter < 2) {
#pragma unroll
            for (int q = 0; q < 16; ++q) {
                float v = vj[q * 32 + c] * VINV;   // pre-scale for the raw dot
                vjr[q] = (iter == 0) ? v : vjr[q] + v;
            }
        }
    }

    // outputs: p_out, a_out, concat(out).  canonical idx t: c=t>>4, q=t&15
    {
        float v = vj[(t & 15) * 32 + (t >> 4)];
        out[(size_t)n * CQ + t] = v;
        out[OFF_CAT + (size_t)n * 544 + t] = v;
    }
    if (t < NC) {
        float ao = aout_s[t];
        out[OFF_AOUT + n * 32 + t] = ao;
        out[OFF_CAT + (size_t)n * 544 + 512 + t] = ao;
    }
}

// ---------------------------------------------------------------------------
extern "C" void kernel_launch(void* const* d_in, const int* in_sizes, int n_in,
                              void* d_out, int out_size, void* d_ws, size_t ws_size,
                              hipStream_t stream) {
    const float* x = (const float*)d_in[0];
    const float* wts = (const float*)d_in[1];
    float* out = (float*)d_out;
    uchar* votes = (uchar*)d_ws;   // 57.8 MB fp8

    hipLaunchKernelGGL(votes_k, dim3(7, NI), dim3(256), 0, stream,
                       x, wts, votes);
    hipLaunchKernelGGL(routing_k, dim3(NB), dim3(RT_THREADS), 0, stream,
                       votes, x, out);
}

// Round 18
// 115.618 us; speedup vs baseline: 1.3176x; 1.3176x over previous
//
#include <hip/hip_runtime.h>
#include <hip/hip_fp16.h>
#include <math.h>

// Problem constants
#define NB 392      // n = b*oh*ow = 2*14*14
#define NI 288      // K*K*B = 9*32
#define NC 32       // C
#define NQ 16       // PSIZE
#define CQ 512      // NC*NQ
#define CH 544      // B*(PSIZE+1)
#define EPSV 1e-6f

// votes are fp8 e4m3 scaled by 32; routing descales algebraically.
#define VSCALE 32.0f
#define VINV (1.0f / 32.0f)

// out layout (floats)
#define OFF_AOUT 200704       // NB*CQ
#define OFF_CAT  213248       // OFF_AOUT + NB*NC

#define RT_THREADS 512
#define RT_WAVES 8

typedef _Float16 v4h __attribute__((ext_vector_type(4)));
typedef float v4f __attribute__((ext_vector_type(4)));
typedef float v2f __attribute__((ext_vector_type(2)));

// ---------------------------------------------------------------------------
// Gather from x via the unfold channel-major reinterpret.
__device__ __forceinline__ float gather_x(const float* __restrict__ x, int n, int j) {
    int c_idx = j / 9;
    int rem = j - c_idx * 9;
    int ki = rem / 3;
    int kj = rem - ki * 3;
    int b_ = n / 196;
    int rest = n - b_ * 196;
    int yy = rest / 14;
    int xx = rest - yy * 14;
    int iy = yy + ki - 1;
    int ix = xx + kj - 1;
    float v = 0.f;
    if ((unsigned)iy < 14u && (unsigned)ix < 14u)
        v = x[((b_ * 14 + iy) * 14 + ix) * CH + c_idx];
    return v;
}

// ---------------------------------------------------------------------------
// votes via swapped-operand mfma 16x16x16 f16, reading wts directly.
// (Round-16 structure -- measured best.)
__global__ __launch_bounds__(256) void votes_k(const float* __restrict__ x,
                                               const float* __restrict__ wts,
                                               uchar* __restrict__ votes) {
    __shared__ uint tile[64 * 36];      // 9 KB, pitch 36 dwords (144 B)
    int mtt = blockIdx.x;         // 0..6
    int i = blockIdx.y;           // 0..287
    int t = threadIdx.x;
    int wv = t >> 6;
    int l = t & 63;
    int col = l & 15;
    int quad = l >> 4;

    int n_row = mtt * 64 + wv * 16 + col;
    v4h av = {};
    if (n_row < NB) {
        int jb = (i >> 5) * CH + (i & 31) * 16 + quad * 4;
#pragma unroll
        for (int kk = 0; kk < 4; ++kk)
            av[kk] = (_Float16)gather_x(x, n_row, jb + kk);
    }

    const float* wb = wts + (size_t)i * 8192 + quad * 64 + col;
    const uchar* tileb = (const uchar*)tile;

    for (int ch = 0; ch < 4; ++ch) {
#pragma unroll
        for (int c8 = 0; c8 < 8; ++c8) {
            int ct = ch * 8 + c8;
            const float* wp = wb + ct * 256;
            v4h bv;
            bv[0] = (_Float16)wp[0];
            bv[1] = (_Float16)wp[16];
            bv[2] = (_Float16)wp[32];
            bv[3] = (_Float16)wp[48];
            v4f acc = {0.f, 0.f, 0.f, 0.f};
            acc = __builtin_amdgcn_mfma_f32_16x16x16f16(bv, av, acc, 0, 0, 0);
            uint u = __builtin_amdgcn_cvt_pk_fp8_f32(acc[0] * VSCALE, acc[1] * VSCALE, 0, false);
            u = __builtin_amdgcn_cvt_pk_fp8_f32(acc[2] * VSCALE, acc[3] * VSCALE, u, true);
            tile[(wv * 16 + col) * 36 + c8 * 4 + quad] = u;
        }
        __syncthreads();
#pragma unroll
        for (int k = 0; k < 2; ++k) {
            int idx = k * 256 + t;
            int row = idx >> 3;
            int off = idx & 7;
            int n_out = mtt * 64 + row;
            if (n_out < NB) {
                uint4 d = *(const uint4*)&tileb[row * 144 + off * 16];
                *(uint4*)(votes + (((size_t)n_out * NI + i) << 9) + ch * 128 + off * 16) = d;
            }
        }
        __syncthreads();
    }
}

// ---------------------------------------------------------------------------
// Fused dynamic routing, 3 global passes over fp8 votes (round-16 version --
// measured best). Round 17 proved routing is latency/TLP-bound, NOT HBM-bound:
// LDS-residency cut FETCH 157->30 MB but doubled dur (1 block/CU, 8 waves).
// This version keeps 16 KB sred -> 12+ waves/CU so the L3-served re-read
// passes overlap across waves. Block = n, 512 threads; lane c = l&31,
// g = l>>5; wave wv step s handles i = (s*8+wv)*2+g. vjr pre-scaled x1/32.
// Scratch [q*32+c] conflict-free. Depth-4 prefetch.
__global__ __launch_bounds__(RT_THREADS) void routing_k(const uchar* __restrict__ votes,
                                                        const float* __restrict__ x,
                                                        float* __restrict__ out) {
    __shared__ float afs[NI];
    __shared__ float sred[RT_WAVES * CQ];   // 16 KB, [group][q*32+c]
    __shared__ float vj[CQ];                // [q*32+c]
    __shared__ float aout_s[NC];

    int n = blockIdx.x;
    int t = threadIdx.x;
    int wv = t >> 6;      // 0..7
    int l = t & 63;
    int c = l & 31;
    int g = l >> 5;

    if (t < NI) {
        int j = (t >> 5) * CH + 512 + (t & 31);
        float v = gather_x(x, n, j);
        float a = fminf(fmaxf(v, 1e-4f), 1.0f);
        afs[t] = a / (a + EPSV);
    }
    __syncthreads();

    const uchar* vb = votes + (size_t)n * NI * 512;
    float vjr[16];    // cumulative vj, PRE-SCALED by 1/32
    float sreg[16];

#define VROW(S) (((const uint4*)(vb + ((size_t)(((((S) << 3) + wv) << 1) + g) << 9)))[c])

    for (int iter = 0; iter < 3; ++iter) {
#pragma unroll
        for (int q = 0; q < 16; ++q) sreg[q] = 0.f;

        uint4 f0 = VROW(0), f1 = VROW(1), f2 = VROW(2), f3 = VROW(3);

#pragma clang loop unroll_count(2)
        for (int s = 0; s < 18; ++s) {
            int i = ((s << 3) + wv) * 2 + g;
            uint4 cur = f0;
            f0 = f1; f1 = f2; f2 = f3;
            if (s + 4 < 18) f3 = VROW(s + 4);

            float vt[16];   // raw fp8-decoded (x32-scaled votes)
            {
                v2f p;
                p = __builtin_amdgcn_cvt_pk_f32_fp8(cur.x, false); vt[0] = p[0];  vt[1] = p[1];
                p = __builtin_amdgcn_cvt_pk_f32_fp8(cur.x, true);  vt[2] = p[0];  vt[3] = p[1];
                p = __builtin_amdgcn_cvt_pk_f32_fp8(cur.y, false); vt[4] = p[0];  vt[5] = p[1];
                p = __builtin_amdgcn_cvt_pk_f32_fp8(cur.y, true);  vt[6] = p[0];  vt[7] = p[1];
                p = __builtin_amdgcn_cvt_pk_f32_fp8(cur.z, false); vt[8] = p[0];  vt[9] = p[1];
                p = __builtin_amdgcn_cvt_pk_f32_fp8(cur.z, true);  vt[10] = p[0]; vt[11] = p[1];
                p = __builtin_amdgcn_cvt_pk_f32_fp8(cur.w, false); vt[12] = p[0]; vt[13] = p[1];
                p = __builtin_amdgcn_cvt_pk_f32_fp8(cur.w, true);  vt[14] = p[0]; vt[15] = p[1];
            }
            float cij;
            if (iter == 0) {
                cij = afs[i] * (1.0f / 32.0f);
            } else {
                float ah = 0.f;   // vt(raw) . vjr(pre-scaled) == true dot
#pragma unroll
                for (int q = 0; q < 16; ++q) ah += vt[q] * vjr[q];
                float e = __expf(ah);
                float ssum = e;
                ssum += __shfl_xor(ssum, 1);
                ssum += __shfl_xor(ssum, 2);
                ssum += __shfl_xor(ssum, 4);
                ssum += __shfl_xor(ssum, 8);
                ssum += __shfl_xor(ssum, 16);
                cij = e * __builtin_amdgcn_rcpf(ssum) * afs[i];
            }
#pragma unroll
            for (int q = 0; q < 16; ++q) sreg[q] += cij * vt[q];
        }

        // fold g-halves, write 8 partial groups (layout [q*32+c]: bank==c)
#pragma unroll
        for (int q = 0; q < 16; ++q) sreg[q] += __shfl_xor(sreg[q], 32);
        if (g == 0) {
            float* sw = &sred[wv * CQ + c];
#pragma unroll
            for (int q = 0; q < 16; ++q) sw[q * 32] = sreg[q];
        }
        __syncthreads();
        {
            float ssum = 0.f;   // 512 threads == CQ columns
#pragma unroll
            for (int k = 0; k < RT_WAVES; ++k) ssum += sred[k * CQ + t];
            sred[t] = ssum * VINV;   // descale the x32 fp8 encoding ONCE
        }
        __syncthreads();

        // squash (threads 0..31, one c each; element (c,q) at sred[q*32+c])
        if (t < NC) {
            float s2 = 0.f;
#pragma unroll
            for (int q = 0; q < 16; ++q) {
                float s = sred[q * 32 + t];
                s2 += s * s;
            }
            float f = (s2 / (1.f + s2)) / sqrtf(s2 + EPSV);
            float vn2 = 0.f;
#pragma unroll
            for (int q = 0; q < 16; ++q) {
                float v = f * sred[q * 32 + t];
                vj[q * 32 + t] = v;
                vn2 += v * v;
            }
            if (iter == 2) {
                float ao = sqrtf(vn2 + EPSV);
                ao = fminf(fmaxf(ao, 1e-4f), 1.f - 1e-4f);
                aout_s[t] = ao;
            }
        }
        __syncthreads();
        if (iter < 2) {
#pragma unroll
            for (int q = 0; q < 16; ++q) {
                float v = vj[q * 32 + c] * VINV;   // pre-scale for the raw dot
                vjr[q] = (iter == 0) ? v : vjr[q] + v;
            }
        }
    }

    // outputs: p_out, a_out, concat(out).  canonical idx t: c=t>>4, q=t&15
    {
        float v = vj[(t & 15) * 32 + (t >> 4)];
        out[(size_t)n * CQ + t] = v;
        out[OFF_CAT + (size_t)n * 544 + t] = v;
    }
    if (t < NC) {
        float ao = aout_s[t];
        out[OFF_AOUT + n * 32 + t] = ao;
        out[OFF_CAT + (size_t)n * 544 + 512 + t] = ao;
    }
}

// ---------------------------------------------------------------------------
extern "C" void kernel_launch(void* const* d_in, const int* in_sizes, int n_in,
                              void* d_out, int out_size, void* d_ws, size_t ws_size,
                              hipStream_t stream) {
    const float* x = (const float*)d_in[0];
    const float* wts = (const float*)d_in[1];
    float* out = (float*)d_out;
    uchar* votes = (uchar*)d_ws;   // 57.8 MB fp8

    hipLaunchKernelGGL(votes_k, dim3(7, NI), dim3(256), 0, stream,
                       x, wts, votes);
    hipLaunchKernelGGL(routing_k, dim3(NB), dim3(RT_THREADS), 0, stream,
                       votes, x, out);
}